// Round 8
// baseline (273.827 us; speedup 1.0000x reference)
//
#include <hip/hip_runtime.h>
#include <hip/hip_bf16.h>
#include <stdint.h>

typedef unsigned long long u64;

#define S 16            // slices per row
#define NB 8192         // histogram bins = top 13 bits of monotone float key
#define KSHIFT 19       // 32-13
#define TKMARGIN 64     // candidates kept beyond top_k
#define CAND_MAX 4096   // global per-row candidate capacity
#define NT1 256
#define NT3 256
#define NT4 1024
#define NW4 (NT4 / 64)
#define ITER1 8         // register-staged float4s per thread in pass1

__device__ __forceinline__ unsigned fkey(float x) {
    unsigned u = __float_as_uint(x);
    return ((int)u < 0) ? ~u : (u | 0x80000000u);
}

// ---------------- K0: fast workspace zero ----------------
__global__ __launch_bounds__(256) void k_zero(uint4* __restrict__ p, int n16)
{
    const uint4 z = make_uint4(0u, 0u, 0u, 0u);
    for (int i = blockIdx.x * 256 + threadIdx.x; i < n16; i += gridDim.x * 256)
        p[i] = z;
}

// ---------------- K1: single sweep: slice max + exp-sum(slice max) + histogram ----
__global__ __launch_bounds__(NT1) void k_pass1(
    const float* __restrict__ logits, const float* __restrict__ temps,
    float* __restrict__ gmax, float* __restrict__ gsum,
    unsigned* __restrict__ ghist, int V, int slen)
{
    const int s = blockIdx.x, b = blockIdx.y, tid = threadIdx.x;
    __shared__ unsigned h[NB];
    __shared__ float red[NT1 / 64];
    __shared__ float s_ms;
    for (int i = tid; i < NB; i += NT1) h[i] = 0u;

    const float t = temps[b];
    const float* xrow = logits + (size_t)b * (size_t)V;
    const int beg = s * slen, end = min(V, beg + slen);
    const float4* x4 = (const float4*)xrow;
    const int beg4 = beg >> 2, end4 = end >> 2;
    const int reg_end = beg4 + ITER1 * NT1;          // register-staged range

    // --- load up to ITER1 float4s into registers (predicated, static unroll) ---
    float4 r[ITER1];
    #pragma unroll
    for (int k = 0; k < ITER1; ++k) {
        int idx = beg4 + k * NT1 + tid;
        r[k] = (idx < end4) ? x4[idx] : make_float4(-INFINITY, -INFINITY, -INFINITY, -INFINITY);
    }

    // --- slice max ---
    float lmax = -INFINITY;
    #pragma unroll
    for (int k = 0; k < ITER1; ++k)
        lmax = fmaxf(lmax, fmaxf(fmaxf(r[k].x, r[k].y), fmaxf(r[k].z, r[k].w)));
    for (int idx = reg_end + tid; idx < end4; idx += NT1) {      // residual (0 iters @V=128000)
        float4 v = x4[idx];
        lmax = fmaxf(lmax, fmaxf(fmaxf(v.x, v.y), fmaxf(v.z, v.w)));
    }
    for (int i = max(beg, end4 << 2) + tid; i < end; i += NT1)   // scalar tail
        lmax = fmaxf(lmax, xrow[i]);
    for (int off = 32; off > 0; off >>= 1) lmax = fmaxf(lmax, __shfl_xor(lmax, off));
    if ((tid & 63) == 0) red[tid >> 6] = lmax;
    __syncthreads();
    if (tid == 0) {
        float m = red[0];
        for (int w = 1; w < NT1 / 64; ++w) m = fmaxf(m, red[w]);
        gmax[b * S + s] = m;          // raw slice max
        s_ms = m / t;                 // slice m_s (monotone rounding, same as row form)
    }
    __syncthreads();
    const float ms = s_ms;

    // --- exp-sum vs slice max + histogram from registers ---
    float lsum = 0.f;
    #pragma unroll
    for (int k = 0; k < ITER1; ++k) {
        int idx = beg4 + k * NT1 + tid;
        if (idx < end4) {
            float e0 = expf(r[k].x / t - ms), e1 = expf(r[k].y / t - ms);
            float e2 = expf(r[k].z / t - ms), e3 = expf(r[k].w / t - ms);
            lsum += e0; lsum += e1; lsum += e2; lsum += e3;
            atomicAdd(&h[fkey(r[k].x) >> KSHIFT], 1u);
            atomicAdd(&h[fkey(r[k].y) >> KSHIFT], 1u);
            atomicAdd(&h[fkey(r[k].z) >> KSHIFT], 1u);
            atomicAdd(&h[fkey(r[k].w) >> KSHIFT], 1u);
        }
    }
    for (int idx = reg_end + tid; idx < end4; idx += NT1) {      // residual
        float4 v = x4[idx];
        float e0 = expf(v.x / t - ms), e1 = expf(v.y / t - ms);
        float e2 = expf(v.z / t - ms), e3 = expf(v.w / t - ms);
        lsum += e0; lsum += e1; lsum += e2; lsum += e3;
        atomicAdd(&h[fkey(v.x) >> KSHIFT], 1u);
        atomicAdd(&h[fkey(v.y) >> KSHIFT], 1u);
        atomicAdd(&h[fkey(v.z) >> KSHIFT], 1u);
        atomicAdd(&h[fkey(v.w) >> KSHIFT], 1u);
    }
    for (int i = max(beg, end4 << 2) + tid; i < end; i += NT1) { // scalar tail
        float x = xrow[i];
        float e = expf(x / t - ms);
        lsum += e;
        atomicAdd(&h[fkey(x) >> KSHIFT], 1u);
    }
    for (int off = 32; off > 0; off >>= 1) lsum += __shfl_xor(lsum, off);
    if ((tid & 63) == 0) red[tid >> 6] = lsum;
    __syncthreads();
    if (tid == 0) {
        float sum = 0.f;
        for (int w = 0; w < NT1 / 64; ++w) sum += red[w];
        gsum[b * S + s] = sum;
    }
    unsigned* gh = ghist + (size_t)b * NB;
    for (int i = tid; i < NB; i += NT1)
        if (h[i]) atomicAdd(&gh[i], h[i]);
}

// ---------------- K2: row combine: m, denom, topk-aware threshold ----------------
__global__ __launch_bounds__(64) void k_thr(
    const float* __restrict__ gmax, const float* __restrict__ gsum,
    const float* __restrict__ temps, const int* __restrict__ topks,
    const unsigned* __restrict__ ghist, float* __restrict__ gm,
    float* __restrict__ gden, unsigned* __restrict__ gthr)
{
    const int b = blockIdx.x, lane = threadIdx.x;
    const float t = temps[b];

    float v = (lane < S) ? gmax[b * S + lane] : -INFINITY;
    float vv = v;
    for (int off = 32; off > 0; off >>= 1) vv = fmaxf(vv, __shfl_xor(vv, off));
    const float m = vv / t;                        // row m (same rounding as slices)

    // denom = sum_s sum_s * exp(m_s - m)
    float d = (lane < S) ? gsum[b * S + lane] * expf(v / t - m) : 0.f;
    for (int off = 32; off > 0; off >>= 1) d += __shfl_xor(d, off);

    const unsigned needed = (unsigned)topks[b] + TKMARGIN;

    const unsigned* h = ghist + (size_t)b * NB;
    const int CH = NB / 64;
    const int base = lane * CH;
    unsigned c = 0;
    for (int j = 0; j < CH; ++j) c += h[base + j];
    unsigned tsuf = c;
    for (int off = 1; off < 64; off <<= 1) {
        unsigned o = __shfl_down(tsuf, off);
        if (lane + off < 64) tsuf += o;
    }
    unsigned long long mask = __ballot(tsuf >= needed);
    int lstar = 63 - __builtin_clzll(mask);
    unsigned above = __shfl(tsuf, (lstar + 1) & 63);
    if (lstar == 63) above = 0u;
    if (lane == 0) {
        unsigned run = above;
        int thrbin = lstar * CH;
        for (int bb = lstar * CH + CH - 1; bb >= lstar * CH; --bb) {
            run += h[bb];
            if (run >= needed) { thrbin = bb; break; }
        }
        gthr[b] = (unsigned)thrbin << KSHIFT;
        gm[b] = m;
        gden[b] = d;
    }
}

// ---------------- K3: pure filter: append (x_bits, idx) via ballot compaction ----
__global__ __launch_bounds__(NT3) void k_collect(
    const float* __restrict__ logits, const unsigned* __restrict__ gthr,
    u64* __restrict__ gcand, unsigned* __restrict__ gcnt, int V, int slen)
{
    const int s = blockIdx.x, b = blockIdx.y, tid = threadIdx.x;
    const int lane = tid & 63;
    const unsigned thr = gthr[b];
    const float* xrow = logits + (size_t)b * (size_t)V;
    const int beg = s * slen, end = min(V, beg + slen);
    const float4* x4 = (const float4*)xrow;
    const int beg4 = beg >> 2, end4 = end >> 2;
    u64* dst = gcand + (size_t)b * CAND_MAX;

    for (int i = beg4 + tid; i < end4; i += NT3) {
        float4 v = x4[i];
        const int i0 = i << 2;
        #pragma unroll
        for (int c = 0; c < 4; ++c) {
            float x = (c == 0) ? v.x : (c == 1) ? v.y : (c == 2) ? v.z : v.w;
            bool pred = fkey(x) >= thr;
            u64 mk = __ballot(pred);
            if (mk) {
                unsigned base;
                if (lane == 0) base = atomicAdd(&gcnt[b], (unsigned)__popcll(mk));
                base = __shfl(base, 0);
                if (pred) {
                    unsigned pos = base + (unsigned)__popcll(mk & ((1ull << lane) - 1ull));
                    if (pos < CAND_MAX)
                        dst[pos] = ((u64)__float_as_uint(x) << 32) | (unsigned)(i0 + c);
                }
            }
        }
    }
    for (int i = max(beg, end4 << 2) + tid; i < end; i += NT3) {
        float x = xrow[i];
        bool pred = fkey(x) >= thr;
        u64 mk = __ballot(pred);
        if (mk) {
            unsigned base;
            if (lane == 0) base = atomicAdd(&gcnt[b], (unsigned)__popcll(mk));
            base = __shfl(base, 0);
            if (pred) {
                unsigned pos = base + (unsigned)__popcll(mk & ((1ull << lane) - 1ull));
                if (pos < CAND_MAX)
                    dst[pos] = ((u64)__float_as_uint(x) << 32) | (unsigned)i;
            }
        }
    }
}

// ---------------- K4: exp+div on candidates, bitonic sort, scans, sample ----------
__global__ __launch_bounds__(NT4) void k_finish(
    const u64* __restrict__ gcand, const unsigned* __restrict__ gcnt,
    const float* __restrict__ temps, const float* __restrict__ gm,
    const float* __restrict__ gden, const float* __restrict__ minps,
    const float* __restrict__ topps, const int* __restrict__ topks,
    const float* __restrict__ us, int* __restrict__ out)
{
    const int b = blockIdx.x, tid = threadIdx.x;
    __shared__ u64 cand[CAND_MAX];
    __shared__ float wsum[NW4];
    __shared__ unsigned wfirst[NW4];

    const float t = temps[b], m = gm[b], denom = gden[b];
    int n = (int)min(gcnt[b], (unsigned)CAND_MAX);
    const u64* src = gcand + (size_t)b * CAND_MAX;
    for (int i = tid; i < n; i += NT4) {
        u64 w = src[i];
        float x = __uint_as_float((unsigned)(w >> 32));
        float e = expf(x / t - m);
        float p = e / denom;
        cand[i] = ((u64)__float_as_uint(p) << 32) | (unsigned)(~(unsigned)w);
    }
    int n2 = 1; while (n2 < n) n2 <<= 1;
    for (int i = n + tid; i < n2; i += NT4) cand[i] = 0ULL;
    __syncthreads();

    // bitonic sort, descending by (p_bits, ~idx)
    for (int k = 2; k <= n2; k <<= 1) {
        for (int j = k >> 1; j > 0; j >>= 1) {
            for (int i = tid; i < n2; i += NT4) {
                int ixj = i ^ j;
                if (ixj > i) {
                    u64 a = cand[i], bb = cand[ixj];
                    bool sw = ((i & k) == 0) ? (a < bb) : (a > bb);
                    if (sw) { cand[i] = bb; cand[ixj] = a; }
                }
            }
            __syncthreads();
        }
    }

    // ---- parallel epilogue: thread i owns sorted element i ----
    const int lane = tid & 63, wv = tid >> 6;
    const float topp = topps[b], minp = minps[b], uu = us[b];
    int tk = topks[b];
    if (tk > n) tk = n;
    if (tk > NT4) tk = NT4;

    float p = 0.f;
    if (tid < tk) p = __uint_as_float((unsigned)(cand[tid] >> 32));

    float c = p;
    #pragma unroll
    for (int off = 1; off < 64; off <<= 1) {
        float o = __shfl_up(c, off);
        if (lane >= off) c += o;
    }
    if (lane == 63) wsum[wv] = c;
    __syncthreads();
    if (tid < 64) {
        float sv = (tid < NW4) ? wsum[tid] : 0.f;
        #pragma unroll
        for (int off = 1; off < NW4; off <<= 1) {
            float o = __shfl_up(sv, off);
            if (tid >= off) sv += o;
        }
        if (tid < NW4) wsum[tid] = sv;
    }
    __syncthreads();
    float cum = c + ((wv > 0) ? wsum[wv - 1] : 0.f);
    float excl = cum - p;                       // replicate (cumsum - p) rounding shape
    float p0 = __uint_as_float((unsigned)(cand[0] >> 32));
    float thrmp = p0 * minp;
    float p1v = (excl <= topp) ? p : 0.f;
    float v = (p1v >= thrmp) ? p1v : 0.f;
    __syncthreads();

    float cv = v;
    #pragma unroll
    for (int off = 1; off < 64; off <<= 1) {
        float o = __shfl_up(cv, off);
        if (lane >= off) cv += o;
    }
    if (lane == 63) wsum[wv] = cv;
    __syncthreads();
    if (tid < 64) {
        float sv = (tid < NW4) ? wsum[tid] : 0.f;
        #pragma unroll
        for (int off = 1; off < NW4; off <<= 1) {
            float o = __shfl_up(sv, off);
            if (tid >= off) sv += o;
        }
        if (tid < NW4) wsum[tid] = sv;
    }
    __syncthreads();
    float cdf = cv + ((wv > 0) ? wsum[wv - 1] : 0.f);
    float total = wsum[NW4 - 1];
    float target = uu * total;

    bool hit = (tid < tk) && (cdf > target);
    u64 mk = __ballot(hit);
    if (lane == 0) wfirst[wv] = mk ? (unsigned)__builtin_ctzll(mk) : 0xFFFFFFFFu;
    __syncthreads();
    if (tid == 0) {
        int sel = -1;
        for (int w = 0; w < NW4; ++w)
            if (wfirst[w] != 0xFFFFFFFFu) { sel = w * 64 + (int)wfirst[w]; break; }
        if (sel < 0) sel = 0;
        out[b] = (int)~(unsigned)cand[sel];
    }
}

// ---------------- Fallback: monolithic single kernel (round-1, passed) ----------------
#define FNT 512
#define FNBINS 1024
#define FKMARGIN 1224
__global__ __launch_bounds__(FNT) void sampler_mono(
    const float* __restrict__ logits, const float* __restrict__ temps,
    const float* __restrict__ minps, const float* __restrict__ topps,
    const int* __restrict__ topks, const float* __restrict__ us,
    int* __restrict__ out, int V)
{
    const int row = blockIdx.x;
    const int tid = threadIdx.x;
    const float t = temps[row];
    __shared__ unsigned int hist[FNBINS];
    __shared__ u64 cand[CAND_MAX];
    __shared__ float red[FNT / 64];
    __shared__ float s_m, s_denom;
    __shared__ unsigned s_thr, s_cnt;
    for (int i = tid; i < FNBINS; i += FNT) hist[i] = 0u;
    if (tid == 0) s_cnt = 0u;
    const float* xrow = logits + (size_t)row * (size_t)V;
    const int n4 = V >> 2;
    const float4* x4 = (const float4*)xrow;
    float lmax = -INFINITY;
    for (int i = tid; i < n4; i += FNT) {
        float4 v = x4[i];
        lmax = fmaxf(lmax, fmaxf(fmaxf(v.x, v.y), fmaxf(v.z, v.w)));
    }
    for (int i = (n4 << 2) + tid; i < V; i += FNT) lmax = fmaxf(lmax, xrow[i]);
    for (int off = 32; off > 0; off >>= 1) lmax = fmaxf(lmax, __shfl_xor(lmax, off));
    if ((tid & 63) == 0) red[tid >> 6] = lmax;
    __syncthreads();
    if (tid == 0) {
        float r = red[0];
        for (int w = 1; w < FNT / 64; ++w) r = fmaxf(r, red[w]);
        s_m = r / t;
    }
    __syncthreads();
    const float m = s_m;
    float lsum = 0.f;
    for (int i = tid; i < n4; i += FNT) {
        float4 v = x4[i];
        float e0 = expf(v.x / t - m), e1 = expf(v.y / t - m);
        float e2 = expf(v.z / t - m), e3 = expf(v.w / t - m);
        lsum += e0; lsum += e1; lsum += e2; lsum += e3;
        atomicAdd(&hist[__float_as_uint(e0) >> 20], 1u);
        atomicAdd(&hist[__float_as_uint(e1) >> 20], 1u);
        atomicAdd(&hist[__float_as_uint(e2) >> 20], 1u);
        atomicAdd(&hist[__float_as_uint(e3) >> 20], 1u);
    }
    for (int i = (n4 << 2) + tid; i < V; i += FNT) {
        float e = expf(xrow[i] / t - m);
        lsum += e;
        atomicAdd(&hist[__float_as_uint(e) >> 20], 1u);
    }
    for (int off = 32; off > 0; off >>= 1) lsum += __shfl_xor(lsum, off);
    if ((tid & 63) == 0) red[tid >> 6] = lsum;
    __syncthreads();
    if (tid == 0) {
        float r = 0.f;
        for (int w = 0; w < FNT / 64; ++w) r += red[w];
        s_denom = r;
    }
    __syncthreads();
    const float denom = s_denom;
    if (tid < 64) {
        const int lane = tid;
        const int CH = FNBINS / 64;
        const int base = lane * CH;
        unsigned c = 0;
        #pragma unroll
        for (int j = 0; j < CH; ++j) c += hist[base + j];
        unsigned tsuf = c;
        #pragma unroll
        for (int off = 1; off < 64; off <<= 1) {
            unsigned o = __shfl_down(tsuf, off);
            if (lane + off < 64) tsuf += o;
        }
        unsigned long long mask = __ballot(tsuf >= (unsigned)FKMARGIN);
        int lstar = 63 - __builtin_clzll(mask);
        unsigned above = __shfl(tsuf, (lstar + 1) & 63);
        if (lstar == 63) above = 0u;
        if (lane == 0) {
            unsigned run = above;
            int thrbin = lstar * CH;
            for (int bb = lstar * CH + CH - 1; bb >= lstar * CH; --bb) {
                run += hist[bb];
                if (run >= (unsigned)FKMARGIN) { thrbin = bb; break; }
            }
            s_thr = (unsigned)thrbin << 20;
        }
    }
    __syncthreads();
    const unsigned thrkey = s_thr;
    for (int i = tid; i < n4; i += FNT) {
        float4 v = x4[i];
        float e[4] = { expf(v.x / t - m), expf(v.y / t - m),
                       expf(v.z / t - m), expf(v.w / t - m) };
        #pragma unroll
        for (int c = 0; c < 4; ++c) {
            unsigned eb = __float_as_uint(e[c]);
            if (eb >= thrkey) {
                float p = e[c] / denom;
                unsigned pos = atomicAdd(&s_cnt, 1u);
                if (pos < CAND_MAX)
                    cand[pos] = ((u64)__float_as_uint(p) << 32) | (unsigned)(~(unsigned)((i << 2) + c));
            }
        }
    }
    for (int i = (n4 << 2) + tid; i < V; i += FNT) {
        float e = expf(xrow[i] / t - m);
        if (__float_as_uint(e) >= thrkey) {
            float p = e / denom;
            unsigned pos = atomicAdd(&s_cnt, 1u);
            if (pos < CAND_MAX)
                cand[pos] = ((u64)__float_as_uint(p) << 32) | (unsigned)(~(unsigned)i);
        }
    }
    __syncthreads();
    int n = (int)s_cnt; if (n > CAND_MAX) n = CAND_MAX;
    int n2 = 1; while (n2 < n) n2 <<= 1;
    for (int i = n + tid; i < n2; i += FNT) cand[i] = 0ULL;
    __syncthreads();
    for (int k = 2; k <= n2; k <<= 1) {
        for (int j = k >> 1; j > 0; j >>= 1) {
            for (int i = tid; i < n2; i += FNT) {
                int ixj = i ^ j;
                if (ixj > i) {
                    u64 a = cand[i], bb = cand[ixj];
                    bool sw = ((i & k) == 0) ? (a < bb) : (a > bb);
                    if (sw) { cand[i] = bb; cand[ixj] = a; }
                }
            }
            __syncthreads();
        }
    }
    if (tid == 0) {
        const float topp = topps[row], minp = minps[row], uu = us[row];
        int tk = topks[row];
        if (tk > n) tk = n;
        float p0 = __uint_as_float((unsigned)(cand[0] >> 32));
        float thrmp = p0 * minp;
        float cum = 0.f, total = 0.f;
        for (int i = 0; i < tk; ++i) {
            float p = __uint_as_float((unsigned)(cand[i] >> 32));
            cum = cum + p;
            float excl = cum - p;
            float p1 = (excl <= topp) ? p : 0.f;
            float v = (p1 >= thrmp) ? p1 : 0.f;
            total += v;
        }
        float target = uu * total;
        float cdf = 0.f; int sel = -1;
        cum = 0.f;
        for (int i = 0; i < tk; ++i) {
            float p = __uint_as_float((unsigned)(cand[i] >> 32));
            cum = cum + p;
            float excl = cum - p;
            float p1 = (excl <= topp) ? p : 0.f;
            float v = (p1 >= thrmp) ? p1 : 0.f;
            cdf += v;
            if (cdf > target) { sel = i; break; }
        }
        if (sel < 0) sel = 0;
        out[row] = (int)~(unsigned)cand[sel];
    }
}

extern "C" void kernel_launch(void* const* d_in, const int* in_sizes, int n_in,
                              void* d_out, int out_size, void* d_ws, size_t ws_size,
                              hipStream_t stream) {
    const float* logits = (const float*)d_in[0];
    const float* temps  = (const float*)d_in[1];
    const float* minps  = (const float*)d_in[2];
    const float* topps  = (const float*)d_in[3];
    const int*   topks  = (const int*)d_in[4];
    const float* us     = (const float*)d_in[5];
    const int B = in_sizes[1];
    const int V = in_sizes[0] / B;
    int* outp = (int*)d_out;

    const int slen = (((V + S - 1) / S) + 3) & ~3;   // slice length, mult of 4

    size_t need = 0;
    const size_t off_cand = need; need += (size_t)B * CAND_MAX * sizeof(u64);
    const size_t off_hist = need; need += (size_t)B * NB * sizeof(unsigned);
    const size_t off_cnt  = need; need += (size_t)B * sizeof(unsigned);
    const size_t off_max  = need; need += (size_t)B * S * sizeof(float);
    const size_t off_sum  = need; need += (size_t)B * S * sizeof(float);
    const size_t off_m    = need; need += (size_t)B * sizeof(float);
    const size_t off_den  = need; need += (size_t)B * sizeof(float);
    const size_t off_thr  = need; need += (size_t)B * sizeof(unsigned);

    if (ws_size < need) {
        sampler_mono<<<dim3(B), dim3(FNT), 0, stream>>>(
            logits, temps, minps, topps, topks, us, outp, V);
        return;
    }

    char* w = (char*)d_ws;
    u64*      gcand = (u64*)(w + off_cand);
    unsigned* ghist = (unsigned*)(w + off_hist);
    unsigned* gcnt  = (unsigned*)(w + off_cnt);
    float*    gmax  = (float*)(w + off_max);
    float*    gsum  = (float*)(w + off_sum);
    float*    gm    = (float*)(w + off_m);
    float*    gden  = (float*)(w + off_den);
    unsigned* gthr  = (unsigned*)(w + off_thr);

    // zero ghist + gcnt (contiguous, 16B-aligned)
    {
        const size_t zbytes = (size_t)B * NB * sizeof(unsigned) + (size_t)B * sizeof(unsigned);
        const int n16 = (int)(zbytes / 16);
        k_zero<<<dim3(1024), dim3(256), 0, stream>>>((uint4*)ghist, n16);
    }

    k_pass1<<<dim3(S, B), dim3(NT1), 0, stream>>>(logits, temps, gmax, gsum, ghist, V, slen);
    k_thr<<<dim3(B), dim3(64), 0, stream>>>(gmax, gsum, temps, topks, ghist, gm, gden, gthr);
    k_collect<<<dim3(S, B), dim3(NT3), 0, stream>>>(logits, gthr, gcand, gcnt, V, slen);
    k_finish<<<dim3(B), dim3(NT4), 0, stream>>>(
        gcand, gcnt, temps, gm, gden, minps, topps, topks, us, outp);
}

// Round 9
// 92.977 us; speedup vs baseline: 2.9451x; 2.9451x over previous
//
#include <hip/hip_runtime.h>
#include <hip/hip_bf16.h>
#include <stdint.h>

typedef unsigned long long u64;

#define S 16            // slices per row
#define NB 8192         // histogram bins = top 13 bits of monotone float key
#define KSHIFT 19       // 32-13
#define TKMARGIN 128    // candidates kept beyond top_k
#define CAND_MAX 4096   // global per-row candidate capacity
#define LCAP 2048       // per-block (per-slice) candidate capacity
#define NT1 256
#define NT3 256
#define NT4 1024
#define NW4 (NT4 / 64)
#define ITER1 8         // register-staged float4s per thread in pass1

__device__ __forceinline__ unsigned fkey(float x) {
    unsigned u = __float_as_uint(x);
    return ((int)u < 0) ? ~u : (u | 0x80000000u);
}

// ---------------- K0: fast workspace zero ----------------
__global__ __launch_bounds__(256) void k_zero(uint4* __restrict__ p, int n16)
{
    const uint4 z = make_uint4(0u, 0u, 0u, 0u);
    for (int i = blockIdx.x * 256 + threadIdx.x; i < n16; i += gridDim.x * 256)
        p[i] = z;
}

// ---------------- K1: single sweep: slice max + exp-sum(slice max) + histogram ----
__global__ __launch_bounds__(NT1) void k_pass1(
    const float* __restrict__ logits, const float* __restrict__ temps,
    float* __restrict__ gmax, float* __restrict__ gsum,
    unsigned* __restrict__ ghist, int V, int slen)
{
    const int s = blockIdx.x, b = blockIdx.y, tid = threadIdx.x;
    __shared__ unsigned h[NB];
    __shared__ float red[NT1 / 64];
    __shared__ float s_ms;
    for (int i = tid; i < NB; i += NT1) h[i] = 0u;

    const float t = temps[b];
    const float* xrow = logits + (size_t)b * (size_t)V;
    const int beg = s * slen, end = min(V, beg + slen);
    const float4* x4 = (const float4*)xrow;
    const int beg4 = beg >> 2, end4 = end >> 2;
    const int reg_end = beg4 + ITER1 * NT1;          // register-staged range

    // --- load up to ITER1 float4s into registers (predicated, static unroll) ---
    float4 r[ITER1];
    #pragma unroll
    for (int k = 0; k < ITER1; ++k) {
        int idx = beg4 + k * NT1 + tid;
        r[k] = (idx < end4) ? x4[idx] : make_float4(-INFINITY, -INFINITY, -INFINITY, -INFINITY);
    }

    // --- slice max ---
    float lmax = -INFINITY;
    #pragma unroll
    for (int k = 0; k < ITER1; ++k)
        lmax = fmaxf(lmax, fmaxf(fmaxf(r[k].x, r[k].y), fmaxf(r[k].z, r[k].w)));
    for (int idx = reg_end + tid; idx < end4; idx += NT1) {      // residual (0 iters @V=128000)
        float4 v = x4[idx];
        lmax = fmaxf(lmax, fmaxf(fmaxf(v.x, v.y), fmaxf(v.z, v.w)));
    }
    for (int i = max(beg, end4 << 2) + tid; i < end; i += NT1)   // scalar tail
        lmax = fmaxf(lmax, xrow[i]);
    for (int off = 32; off > 0; off >>= 1) lmax = fmaxf(lmax, __shfl_xor(lmax, off));
    if ((tid & 63) == 0) red[tid >> 6] = lmax;
    __syncthreads();
    if (tid == 0) {
        float m = red[0];
        for (int w = 1; w < NT1 / 64; ++w) m = fmaxf(m, red[w]);
        gmax[b * S + s] = m;          // raw slice max
        s_ms = m / t;                 // slice m_s (monotone rounding, same as row form)
    }
    __syncthreads();
    const float ms = s_ms;

    // --- exp-sum vs slice max + histogram from registers ---
    float lsum = 0.f;
    #pragma unroll
    for (int k = 0; k < ITER1; ++k) {
        int idx = beg4 + k * NT1 + tid;
        if (idx < end4) {
            float e0 = expf(r[k].x / t - ms), e1 = expf(r[k].y / t - ms);
            float e2 = expf(r[k].z / t - ms), e3 = expf(r[k].w / t - ms);
            lsum += e0; lsum += e1; lsum += e2; lsum += e3;
            atomicAdd(&h[fkey(r[k].x) >> KSHIFT], 1u);
            atomicAdd(&h[fkey(r[k].y) >> KSHIFT], 1u);
            atomicAdd(&h[fkey(r[k].z) >> KSHIFT], 1u);
            atomicAdd(&h[fkey(r[k].w) >> KSHIFT], 1u);
        }
    }
    for (int idx = reg_end + tid; idx < end4; idx += NT1) {      // residual
        float4 v = x4[idx];
        float e0 = expf(v.x / t - ms), e1 = expf(v.y / t - ms);
        float e2 = expf(v.z / t - ms), e3 = expf(v.w / t - ms);
        lsum += e0; lsum += e1; lsum += e2; lsum += e3;
        atomicAdd(&h[fkey(v.x) >> KSHIFT], 1u);
        atomicAdd(&h[fkey(v.y) >> KSHIFT], 1u);
        atomicAdd(&h[fkey(v.z) >> KSHIFT], 1u);
        atomicAdd(&h[fkey(v.w) >> KSHIFT], 1u);
    }
    for (int i = max(beg, end4 << 2) + tid; i < end; i += NT1) { // scalar tail
        float x = xrow[i];
        float e = expf(x / t - ms);
        lsum += e;
        atomicAdd(&h[fkey(x) >> KSHIFT], 1u);
    }
    for (int off = 32; off > 0; off >>= 1) lsum += __shfl_xor(lsum, off);
    if ((tid & 63) == 0) red[tid >> 6] = lsum;
    __syncthreads();
    if (tid == 0) {
        float sum = 0.f;
        for (int w = 0; w < NT1 / 64; ++w) sum += red[w];
        gsum[b * S + s] = sum;
    }
    unsigned* gh = ghist + (size_t)b * NB;
    for (int i = tid; i < NB; i += NT1)
        if (h[i]) atomicAdd(&gh[i], h[i]);
}

// ---------------- K2: row combine: m, denom, topk-aware threshold ----------------
__global__ __launch_bounds__(64) void k_thr(
    const float* __restrict__ gmax, const float* __restrict__ gsum,
    const float* __restrict__ temps, const int* __restrict__ topks,
    const unsigned* __restrict__ ghist, float* __restrict__ gm,
    float* __restrict__ gden, unsigned* __restrict__ gthr)
{
    const int b = blockIdx.x, lane = threadIdx.x;
    const float t = temps[b];

    float v = (lane < S) ? gmax[b * S + lane] : -INFINITY;
    float vv = v;
    for (int off = 32; off > 0; off >>= 1) vv = fmaxf(vv, __shfl_xor(vv, off));
    const float m = vv / t;                        // row m (same rounding as slices)

    // denom = sum_s sum_s * exp(m_s - m)
    float d = (lane < S) ? gsum[b * S + lane] * expf(v / t - m) : 0.f;
    for (int off = 32; off > 0; off >>= 1) d += __shfl_xor(d, off);

    const unsigned needed = (unsigned)topks[b] + TKMARGIN;

    const unsigned* h = ghist + (size_t)b * NB;
    const int CH = NB / 64;
    const int base = lane * CH;
    unsigned c = 0;
    for (int j = 0; j < CH; ++j) c += h[base + j];
    unsigned tsuf = c;
    for (int off = 1; off < 64; off <<= 1) {
        unsigned o = __shfl_down(tsuf, off);
        if (lane + off < 64) tsuf += o;
    }
    unsigned long long mask = __ballot(tsuf >= needed);
    int lstar = 63 - __builtin_clzll(mask);
    unsigned above = __shfl(tsuf, (lstar + 1) & 63);
    if (lstar == 63) above = 0u;
    if (lane == 0) {
        unsigned run = above;
        int thrbin = lstar * CH;
        for (int bb = lstar * CH + CH - 1; bb >= lstar * CH; --bb) {
            run += h[bb];
            if (run >= needed) { thrbin = bb; break; }
        }
        gthr[b] = (unsigned)thrbin << KSHIFT;
        gm[b] = m;
        gden[b] = d;
    }
}

// ---------------- K3: filter via LDS staging; ONE global atomic per block ----------
__global__ __launch_bounds__(NT3) void k_collect(
    const float* __restrict__ logits, const unsigned* __restrict__ gthr,
    u64* __restrict__ gcand, unsigned* __restrict__ gcnt, int V, int slen)
{
    const int s = blockIdx.x, b = blockIdx.y, tid = threadIdx.x;
    __shared__ u64 buf[LCAP];
    __shared__ unsigned s_cnt, s_base;
    if (tid == 0) s_cnt = 0u;
    __syncthreads();

    const unsigned thr = gthr[b];
    const float* xrow = logits + (size_t)b * (size_t)V;
    const int beg = s * slen, end = min(V, beg + slen);
    const float4* x4 = (const float4*)xrow;
    const int beg4 = beg >> 2, end4 = end >> 2;

    for (int i = beg4 + tid; i < end4; i += NT3) {
        float4 v = x4[i];
        const int i0 = i << 2;
        if (fkey(v.x) >= thr) { unsigned p = atomicAdd(&s_cnt, 1u); if (p < LCAP) buf[p] = ((u64)__float_as_uint(v.x) << 32) | (unsigned)(i0    ); }
        if (fkey(v.y) >= thr) { unsigned p = atomicAdd(&s_cnt, 1u); if (p < LCAP) buf[p] = ((u64)__float_as_uint(v.y) << 32) | (unsigned)(i0 + 1); }
        if (fkey(v.z) >= thr) { unsigned p = atomicAdd(&s_cnt, 1u); if (p < LCAP) buf[p] = ((u64)__float_as_uint(v.z) << 32) | (unsigned)(i0 + 2); }
        if (fkey(v.w) >= thr) { unsigned p = atomicAdd(&s_cnt, 1u); if (p < LCAP) buf[p] = ((u64)__float_as_uint(v.w) << 32) | (unsigned)(i0 + 3); }
    }
    for (int i = max(beg, end4 << 2) + tid; i < end; i += NT3) {
        float x = xrow[i];
        if (fkey(x) >= thr) { unsigned p = atomicAdd(&s_cnt, 1u); if (p < LCAP) buf[p] = ((u64)__float_as_uint(x) << 32) | (unsigned)i; }
    }
    __syncthreads();
    if (tid == 0) {
        unsigned cnt = min(s_cnt, (unsigned)LCAP);
        s_base = atomicAdd(&gcnt[b], cnt);       // the ONLY global atomic
        s_cnt = cnt;
    }
    __syncthreads();
    const unsigned cnt = s_cnt, base = s_base;
    u64* dst = gcand + (size_t)b * CAND_MAX;
    for (unsigned i = tid; i < cnt; i += NT3) {
        unsigned p = base + i;
        if (p < CAND_MAX) dst[p] = buf[i];
    }
}

// ---------------- K4: exp+div on candidates, bitonic sort, scans, sample ----------
__global__ __launch_bounds__(NT4) void k_finish(
    const u64* __restrict__ gcand, const unsigned* __restrict__ gcnt,
    const float* __restrict__ temps, const float* __restrict__ gm,
    const float* __restrict__ gden, const float* __restrict__ minps,
    const float* __restrict__ topps, const int* __restrict__ topks,
    const float* __restrict__ us, int* __restrict__ out)
{
    const int b = blockIdx.x, tid = threadIdx.x;
    __shared__ u64 cand[CAND_MAX];
    __shared__ float wsum[NW4];
    __shared__ unsigned wfirst[NW4];

    const float t = temps[b], m = gm[b], denom = gden[b];
    int n = (int)min(gcnt[b], (unsigned)CAND_MAX);
    const u64* src = gcand + (size_t)b * CAND_MAX;
    for (int i = tid; i < n; i += NT4) {
        u64 w = src[i];
        float x = __uint_as_float((unsigned)(w >> 32));
        float e = expf(x / t - m);
        float p = e / denom;
        cand[i] = ((u64)__float_as_uint(p) << 32) | (unsigned)(~(unsigned)w);
    }
    int n2 = 1; while (n2 < n) n2 <<= 1;
    for (int i = n + tid; i < n2; i += NT4) cand[i] = 0ULL;
    __syncthreads();

    // bitonic sort, descending by (p_bits, ~idx)
    for (int k = 2; k <= n2; k <<= 1) {
        for (int j = k >> 1; j > 0; j >>= 1) {
            for (int i = tid; i < n2; i += NT4) {
                int ixj = i ^ j;
                if (ixj > i) {
                    u64 a = cand[i], bb = cand[ixj];
                    bool sw = ((i & k) == 0) ? (a < bb) : (a > bb);
                    if (sw) { cand[i] = bb; cand[ixj] = a; }
                }
            }
            __syncthreads();
        }
    }

    // ---- parallel epilogue: thread i owns sorted element i ----
    const int lane = tid & 63, wv = tid >> 6;
    const float topp = topps[b], minp = minps[b], uu = us[b];
    int tk = topks[b];
    if (tk > n) tk = n;
    if (tk > NT4) tk = NT4;

    float p = 0.f;
    if (tid < tk) p = __uint_as_float((unsigned)(cand[tid] >> 32));

    float c = p;
    #pragma unroll
    for (int off = 1; off < 64; off <<= 1) {
        float o = __shfl_up(c, off);
        if (lane >= off) c += o;
    }
    if (lane == 63) wsum[wv] = c;
    __syncthreads();
    if (tid < 64) {
        float sv = (tid < NW4) ? wsum[tid] : 0.f;
        #pragma unroll
        for (int off = 1; off < NW4; off <<= 1) {
            float o = __shfl_up(sv, off);
            if (tid >= off) sv += o;
        }
        if (tid < NW4) wsum[tid] = sv;
    }
    __syncthreads();
    float cum = c + ((wv > 0) ? wsum[wv - 1] : 0.f);
    float excl = cum - p;                       // replicate (cumsum - p) rounding shape
    float p0 = __uint_as_float((unsigned)(cand[0] >> 32));
    float thrmp = p0 * minp;
    float p1v = (excl <= topp) ? p : 0.f;
    float v = (p1v >= thrmp) ? p1v : 0.f;
    __syncthreads();

    float cv = v;
    #pragma unroll
    for (int off = 1; off < 64; off <<= 1) {
        float o = __shfl_up(cv, off);
        if (lane >= off) cv += o;
    }
    if (lane == 63) wsum[wv] = cv;
    __syncthreads();
    if (tid < 64) {
        float sv = (tid < NW4) ? wsum[tid] : 0.f;
        #pragma unroll
        for (int off = 1; off < NW4; off <<= 1) {
            float o = __shfl_up(sv, off);
            if (tid >= off) sv += o;
        }
        if (tid < NW4) wsum[tid] = sv;
    }
    __syncthreads();
    float cdf = cv + ((wv > 0) ? wsum[wv - 1] : 0.f);
    float total = wsum[NW4 - 1];
    float target = uu * total;

    bool hit = (tid < tk) && (cdf > target);
    u64 mk = __ballot(hit);
    if (lane == 0) wfirst[wv] = mk ? (unsigned)__builtin_ctzll(mk) : 0xFFFFFFFFu;
    __syncthreads();
    if (tid == 0) {
        int sel = -1;
        for (int w = 0; w < NW4; ++w)
            if (wfirst[w] != 0xFFFFFFFFu) { sel = w * 64 + (int)wfirst[w]; break; }
        if (sel < 0) sel = 0;
        out[b] = (int)~(unsigned)cand[sel];
    }
}

// ---------------- Fallback: monolithic single kernel (round-1, passed) ----------------
#define FNT 512
#define FNBINS 1024
#define FKMARGIN 1224
__global__ __launch_bounds__(FNT) void sampler_mono(
    const float* __restrict__ logits, const float* __restrict__ temps,
    const float* __restrict__ minps, const float* __restrict__ topps,
    const int* __restrict__ topks, const float* __restrict__ us,
    int* __restrict__ out, int V)
{
    const int row = blockIdx.x;
    const int tid = threadIdx.x;
    const float t = temps[row];
    __shared__ unsigned int hist[FNBINS];
    __shared__ u64 cand[CAND_MAX];
    __shared__ float red[FNT / 64];
    __shared__ float s_m, s_denom;
    __shared__ unsigned s_thr, s_cnt;
    for (int i = tid; i < FNBINS; i += FNT) hist[i] = 0u;
    if (tid == 0) s_cnt = 0u;
    const float* xrow = logits + (size_t)row * (size_t)V;
    const int n4 = V >> 2;
    const float4* x4 = (const float4*)xrow;
    float lmax = -INFINITY;
    for (int i = tid; i < n4; i += FNT) {
        float4 v = x4[i];
        lmax = fmaxf(lmax, fmaxf(fmaxf(v.x, v.y), fmaxf(v.z, v.w)));
    }
    for (int i = (n4 << 2) + tid; i < V; i += FNT) lmax = fmaxf(lmax, xrow[i]);
    for (int off = 32; off > 0; off >>= 1) lmax = fmaxf(lmax, __shfl_xor(lmax, off));
    if ((tid & 63) == 0) red[tid >> 6] = lmax;
    __syncthreads();
    if (tid == 0) {
        float r = red[0];
        for (int w = 1; w < FNT / 64; ++w) r = fmaxf(r, red[w]);
        s_m = r / t;
    }
    __syncthreads();
    const float m = s_m;
    float lsum = 0.f;
    for (int i = tid; i < n4; i += FNT) {
        float4 v = x4[i];
        float e0 = expf(v.x / t - m), e1 = expf(v.y / t - m);
        float e2 = expf(v.z / t - m), e3 = expf(v.w / t - m);
        lsum += e0; lsum += e1; lsum += e2; lsum += e3;
        atomicAdd(&hist[__float_as_uint(e0) >> 20], 1u);
        atomicAdd(&hist[__float_as_uint(e1) >> 20], 1u);
        atomicAdd(&hist[__float_as_uint(e2) >> 20], 1u);
        atomicAdd(&hist[__float_as_uint(e3) >> 20], 1u);
    }
    for (int i = (n4 << 2) + tid; i < V; i += FNT) {
        float e = expf(xrow[i] / t - m);
        lsum += e;
        atomicAdd(&hist[__float_as_uint(e) >> 20], 1u);
    }
    for (int off = 32; off > 0; off >>= 1) lsum += __shfl_xor(lsum, off);
    if ((tid & 63) == 0) red[tid >> 6] = lsum;
    __syncthreads();
    if (tid == 0) {
        float r = 0.f;
        for (int w = 0; w < FNT / 64; ++w) r += red[w];
        s_denom = r;
    }
    __syncthreads();
    const float denom = s_denom;
    if (tid < 64) {
        const int lane = tid;
        const int CH = FNBINS / 64;
        const int base = lane * CH;
        unsigned c = 0;
        #pragma unroll
        for (int j = 0; j < CH; ++j) c += hist[base + j];
        unsigned tsuf = c;
        #pragma unroll
        for (int off = 1; off < 64; off <<= 1) {
            unsigned o = __shfl_down(tsuf, off);
            if (lane + off < 64) tsuf += o;
        }
        unsigned long long mask = __ballot(tsuf >= (unsigned)FKMARGIN);
        int lstar = 63 - __builtin_clzll(mask);
        unsigned above = __shfl(tsuf, (lstar + 1) & 63);
        if (lstar == 63) above = 0u;
        if (lane == 0) {
            unsigned run = above;
            int thrbin = lstar * CH;
            for (int bb = lstar * CH + CH - 1; bb >= lstar * CH; --bb) {
                run += hist[bb];
                if (run >= (unsigned)FKMARGIN) { thrbin = bb; break; }
            }
            s_thr = (unsigned)thrbin << 20;
        }
    }
    __syncthreads();
    const unsigned thrkey = s_thr;
    for (int i = tid; i < n4; i += FNT) {
        float4 v = x4[i];
        float e[4] = { expf(v.x / t - m), expf(v.y / t - m),
                       expf(v.z / t - m), expf(v.w / t - m) };
        #pragma unroll
        for (int c = 0; c < 4; ++c) {
            unsigned eb = __float_as_uint(e[c]);
            if (eb >= thrkey) {
                float p = e[c] / denom;
                unsigned pos = atomicAdd(&s_cnt, 1u);
                if (pos < CAND_MAX)
                    cand[pos] = ((u64)__float_as_uint(p) << 32) | (unsigned)(~(unsigned)((i << 2) + c));
            }
        }
    }
    for (int i = (n4 << 2) + tid; i < V; i += FNT) {
        float e = expf(xrow[i] / t - m);
        if (__float_as_uint(e) >= thrkey) {
            float p = e / denom;
            unsigned pos = atomicAdd(&s_cnt, 1u);
            if (pos < CAND_MAX)
                cand[pos] = ((u64)__float_as_uint(p) << 32) | (unsigned)(~(unsigned)i);
        }
    }
    __syncthreads();
    int n = (int)s_cnt; if (n > CAND_MAX) n = CAND_MAX;
    int n2 = 1; while (n2 < n) n2 <<= 1;
    for (int i = n + tid; i < n2; i += FNT) cand[i] = 0ULL;
    __syncthreads();
    for (int k = 2; k <= n2; k <<= 1) {
        for (int j = k >> 1; j > 0; j >>= 1) {
            for (int i = tid; i < n2; i += FNT) {
                int ixj = i ^ j;
                if (ixj > i) {
                    u64 a = cand[i], bb = cand[ixj];
                    bool sw = ((i & k) == 0) ? (a < bb) : (a > bb);
                    if (sw) { cand[i] = bb; cand[ixj] = a; }
                }
            }
            __syncthreads();
        }
    }
    if (tid == 0) {
        const float topp = topps[row], minp = minps[row], uu = us[row];
        int tk = topks[row];
        if (tk > n) tk = n;
        float p0 = __uint_as_float((unsigned)(cand[0] >> 32));
        float thrmp = p0 * minp;
        float cum = 0.f, total = 0.f;
        for (int i = 0; i < tk; ++i) {
            float p = __uint_as_float((unsigned)(cand[i] >> 32));
            cum = cum + p;
            float excl = cum - p;
            float p1 = (excl <= topp) ? p : 0.f;
            float v = (p1 >= thrmp) ? p1 : 0.f;
            total += v;
        }
        float target = uu * total;
        float cdf = 0.f; int sel = -1;
        cum = 0.f;
        for (int i = 0; i < tk; ++i) {
            float p = __uint_as_float((unsigned)(cand[i] >> 32));
            cum = cum + p;
            float excl = cum - p;
            float p1 = (excl <= topp) ? p : 0.f;
            float v = (p1 >= thrmp) ? p1 : 0.f;
            cdf += v;
            if (cdf > target) { sel = i; break; }
        }
        if (sel < 0) sel = 0;
        out[row] = (int)~(unsigned)cand[sel];
    }
}

extern "C" void kernel_launch(void* const* d_in, const int* in_sizes, int n_in,
                              void* d_out, int out_size, void* d_ws, size_t ws_size,
                              hipStream_t stream) {
    const float* logits = (const float*)d_in[0];
    const float* temps  = (const float*)d_in[1];
    const float* minps  = (const float*)d_in[2];
    const float* topps  = (const float*)d_in[3];
    const int*   topks  = (const int*)d_in[4];
    const float* us     = (const float*)d_in[5];
    const int B = in_sizes[1];
    const int V = in_sizes[0] / B;
    int* outp = (int*)d_out;

    const int slen = (((V + S - 1) / S) + 3) & ~3;   // slice length, mult of 4

    size_t need = 0;
    const size_t off_cand = need; need += (size_t)B * CAND_MAX * sizeof(u64);
    const size_t off_hist = need; need += (size_t)B * NB * sizeof(unsigned);
    const size_t off_cnt  = need; need += (size_t)B * sizeof(unsigned);
    const size_t off_max  = need; need += (size_t)B * S * sizeof(float);
    const size_t off_sum  = need; need += (size_t)B * S * sizeof(float);
    const size_t off_m    = need; need += (size_t)B * sizeof(float);
    const size_t off_den  = need; need += (size_t)B * sizeof(float);
    const size_t off_thr  = need; need += (size_t)B * sizeof(unsigned);

    if (ws_size < need) {
        sampler_mono<<<dim3(B), dim3(FNT), 0, stream>>>(
            logits, temps, minps, topps, topks, us, outp, V);
        return;
    }

    char* w = (char*)d_ws;
    u64*      gcand = (u64*)(w + off_cand);
    unsigned* ghist = (unsigned*)(w + off_hist);
    unsigned* gcnt  = (unsigned*)(w + off_cnt);
    float*    gmax  = (float*)(w + off_max);
    float*    gsum  = (float*)(w + off_sum);
    float*    gm    = (float*)(w + off_m);
    float*    gden  = (float*)(w + off_den);
    unsigned* gthr  = (unsigned*)(w + off_thr);

    // zero ghist + gcnt (contiguous, 16B-aligned)
    {
        const size_t zbytes = (size_t)B * NB * sizeof(unsigned) + (size_t)B * sizeof(unsigned);
        const int n16 = (int)(zbytes / 16);
        k_zero<<<dim3(1024), dim3(256), 0, stream>>>((uint4*)ghist, n16);
    }

    k_pass1<<<dim3(S, B), dim3(NT1), 0, stream>>>(logits, temps, gmax, gsum, ghist, V, slen);
    k_thr<<<dim3(B), dim3(64), 0, stream>>>(gmax, gsum, temps, topks, ghist, gm, gden, gthr);
    k_collect<<<dim3(S, B), dim3(NT3), 0, stream>>>(logits, gthr, gcand, gcnt, V, slen);
    k_finish<<<dim3(B), dim3(NT4), 0, stream>>>(
        gcand, gcnt, temps, gm, gden, minps, topps, topks, us, outp);
}